// Round 14
// baseline (228.096 us; speedup 1.0000x reference)
//
#include <hip/hip_runtime.h>

#define ENC_NEGINF 0x007FFFFFu
#define NN_FINE 100000
#define NN_COARSE 1800
#define INV_N  (1.0f / 100000.0f)
#define INV_N2 (1.0f / 1800.0f)

__device__ __forceinline__ unsigned enc_f(float f) {
    unsigned u = __float_as_uint(f);
    return (u & 0x80000000u) ? ~u : (u | 0x80000000u);
}
__device__ __forceinline__ float dec_f(unsigned k) {
    return (k & 0x80000000u) ? __uint_as_float(k & 0x7fffffffu) : __uint_as_float(~k);
}

// bijective XCD-aware swizzle (m204 variant)
__device__ __forceinline__ int xcd_swz(int bid, int nwg) {
    int q = nwg >> 3, r = nwg & 7;
    int xcd = bid & 7, idx = bid >> 3;
    return (xcd < r ? xcd * (q + 1) : r * (q + 1) + (xcd - r) * q) + idx;
}

__device__ __forceinline__ float2 bn_ss(const float* __restrict__ st,
                                        const float* __restrict__ g,
                                        const float* __restrict__ be,
                                        int r, float invn) {
    float mu  = st[r] * invn;
    float var = fmaxf(st[128 + r] * invn - mu * mu, 0.f);
    float s = g[r] * rsqrtf(var + 1e-5f);
    return make_float2(s, be[r] - mu * s);
}

// ---------------- PassA; A1 also zeroes STATS + out --------------------------
// MODE 0: f=in. 1: f=bn(in), write zout=bn(in). 2: f=bn(in)+skipf.
template<int CIN, int COUT, int MODE>
__global__ void pass_a(const float* __restrict__ in,
                       const float* __restrict__ st, const float* __restrict__ g,
                       const float* __restrict__ be, float invn,
                       const float* __restrict__ skipf,
                       const float* __restrict__ wl, const float* __restrict__ wsrc,
                       const float* __restrict__ wpos, const float* __restrict__ bpos,
                       const float* __restrict__ pos,
                       float4* __restrict__ SHP, float2* __restrict__ CAP,
                       float* __restrict__ zout, int total,
                       float* __restrict__ zstats, float* __restrict__ zo) {
    constexpr int P = COUT / 2;
    int idx = blockIdx.x * blockDim.x + threadIdx.x;
    if (zstats) {                    // A1 only: init atomic targets
        if (idx < 1280) zstats[idx] = 0.f;
        if (idx < 808)  zo[idx] = 0.f;
    }
    if (idx >= total) return;
    int i = idx / P, p = idx % P;
    float f[CIN];
#pragma unroll
    for (int r = 0; r < CIN; ++r) {
        float v = in[i * CIN + r];
        if constexpr (MODE >= 1) {
            float2 ss = bn_ss(st, g, be, r, invn);
            v = v * ss.x + ss.y;
        }
        if constexpr (MODE == 2) v += skipf[i * CIN + r];
        f[r] = v;
    }
    int c0 = 2 * p;
    float h0 = 0.f, a0 = 0.f, h1 = 0.f, a1 = 0.f;
#pragma unroll
    for (int r = 0; r < CIN; ++r) {
        float2 wlr = *reinterpret_cast<const float2*>(&wl[r * COUT + c0]);
        float2 wsr = *reinterpret_cast<const float2*>(&wsrc[r * COUT + c0]);
        h0 += f[r] * wlr.x; h1 += f[r] * wlr.y;
        a0 += f[r] * wsr.x; a1 += f[r] * wsr.y;
    }
    float px = pos[i * 3], py = pos[i * 3 + 1], pz = pos[i * 3 + 2];
    float2 w0 = *reinterpret_cast<const float2*>(&wpos[c0]);
    float2 w1 = *reinterpret_cast<const float2*>(&wpos[COUT + c0]);
    float2 w2 = *reinterpret_cast<const float2*>(&wpos[2 * COUT + c0]);
    float pd0 = px * w0.x + py * w1.x + pz * w2.x;
    float pd1 = px * w0.y + py * w1.y + pz * w2.y;
    float2 bp = *reinterpret_cast<const float2*>(&bpos[c0]);
    SHP[(size_t)i * P + p] = make_float4(a0 + pd0, a1 + pd1, h0 - pd0, h1 - pd1);
    CAP[(size_t)i * P + p] = make_float2(pd0 + bp.x, pd1 + bp.y);
    if constexpr (MODE == 1) {
        float2 s0 = bn_ss(st, g, be, c0, invn);
        float2 s1 = bn_ss(st, g, be, c0 + 1, invn);
        float2 zv = make_float2(in[i * CIN + c0] * s0.x + s0.y,
                                in[i * CIN + c0 + 1] * s1.x + s1.y);
        *reinterpret_cast<float2*>(&zout[i * CIN + c0]) = zv;
    }
}

// ---- Edge pass: 1 float4 gather per edge + BN-stats partial rows -----------
template<int C, bool COARSE>
__global__ __launch_bounds__(256, 4)
void edge_pass(const float4* __restrict__ SHP, const float2* __restrict__ CAP,
               const int* __restrict__ esrc, float2* __restrict__ y2,
               float* __restrict__ PS, int NN) {
    constexpr int P = C / 2;
    constexpr int NPB = 256 / P;
    constexpr int DEG_ = COARSE ? 8 : 16;
    __shared__ int se[NPB * DEG_];
    __shared__ float ls[C], lq[C];
    int bid = COARSE ? (int)blockIdx.x : xcd_swz(blockIdx.x, gridDim.x);
    int tid = threadIdx.x;
    int node0 = bid * NPB;
    if constexpr (!COARSE) {
        for (int t = tid; t < NPB * DEG_; t += 256)
            se[t] = esrc[node0 * 16 + t];          // in-bounds: dst half follows src
    } else {
        for (int t = tid; t < NPB * DEG_; t += 256) {
            int n = t / DEG_, e = t % DEG_;
            int i2 = node0 + n;
            if (i2 < NN) {
                int b = i2 / 225, j = i2 % 225;
                se[t] = esrc[b * 1800 + e * 225 + j];
            }
        }
    }
    if (tid < C) { ls[tid] = 0.f; lq[tid] = 0.f; }
    __syncthreads();
    int n = tid / P, p = tid % P;
    int i = node0 + n;
    float y0 = 0.f, y1 = 0.f;
    if (i < NN) {
        float4 q[DEG_ + 1];
#pragma unroll
        for (int e = 0; e < DEG_; ++e)
            q[e] = SHP[(size_t)se[n * DEG_ + e] * P + p];
        q[DEG_] = SHP[(size_t)i * P + p];

        float smin0 = q[0].x, smin1 = q[0].y;
#pragma unroll
        for (int e = 1; e <= DEG_; ++e) {
            smin0 = fminf(smin0, q[e].x);
            smin1 = fminf(smin1, q[e].y);
        }
        float den0 = 0.f, acc0 = 0.f, den1 = 0.f, acc1 = 0.f;
#pragma unroll
        for (int e = 0; e <= DEG_; ++e) {
            float ex0 = __expf(smin0 - q[e].x);
            float ex1 = __expf(smin1 - q[e].y);
            den0 += ex0; acc0 += ex0 * q[e].z;
            den1 += ex1; acc1 += ex1 * q[e].w;
        }
        float2 Ci = CAP[(size_t)i * P + p];
        float o0 = (acc0 + Ci.x * den0) / (den0 + 1e-16f);
        float o1 = (acc1 + Ci.y * den1) / (den1 + 1e-16f);
        y0 = o0 > 0.f ? o0 : (__expf(o0) - 1.f);
        y1 = o1 > 0.f ? o1 : (__expf(o1) - 1.f);
        y2[(size_t)i * P + p] = make_float2(y0, y1);
    }
    float sa0 = y0, sq0 = y0 * y0, sa1 = y1, sq1 = y1 * y1;
    if constexpr (P < 64) {
#pragma unroll
        for (int m = P; m < 64; m <<= 1) {
            sa0 += __shfl_xor(sa0, m); sa1 += __shfl_xor(sa1, m);
            sq0 += __shfl_xor(sq0, m); sq1 += __shfl_xor(sq1, m);
        }
    }
    if ((tid & 63) < P) {
        int c0 = 2 * p;
        atomicAdd(&ls[c0], sa0); atomicAdd(&ls[c0 + 1], sa1);
        atomicAdd(&lq[c0], sq0); atomicAdd(&lq[c0 + 1], sq1);
    }
    __syncthreads();
    if (tid < C) {
        PS[(size_t)blockIdx.x * 2 * C + tid]     = ls[tid];
        PS[(size_t)blockIdx.x * 2 * C + C + tid] = lq[tid];
    }
}

// ------- stats reduce: nb per-block partials -> STATS (multi-block) ---------
template<int C>
__global__ __launch_bounds__(256)
void stats_r(const float* __restrict__ PS, int nb, float* __restrict__ STATS) {
    constexpr int TC = 2 * C;
    constexpr int NS = 256 / TC;
    __shared__ float acc[256];
    int tid = threadIdx.x;
    int c = tid % TC, sl = tid / TC;
    float s = 0.f;
    for (int b = blockIdx.x * NS + sl; b < nb; b += gridDim.x * NS)
        s += PS[(size_t)b * TC + c];
    acc[tid] = s;
    __syncthreads();
    if (tid < TC) {
        float t = 0.f;
#pragma unroll
        for (int s2 = 0; s2 < NS; ++s2) t += acc[s2 * TC + tid];
        float* dst = (tid < C) ? &STATS[tid] : &STATS[128 + (tid - C)];
        atomicAdd(dst, t);
    }
}

// ---- pool3a: 64 blocks/sample, RAW-max private-LDS partials -----------------
__global__ __launch_bounds__(256)
void pool3a(const float* __restrict__ y3, const float* __restrict__ pos,
            unsigned* __restrict__ PK, float* __restrict__ PC,
            float* __restrict__ PP) {
    __shared__ unsigned lkey[7200];
    __shared__ float lcnt[225];
    __shared__ float lpac[675];
    int tid = threadIdx.x;
    for (int t = tid; t < 7200; t += 256) lkey[t] = ENC_NEGINF;
    if (tid < 225) lcnt[tid] = 0.f;
    for (int t = tid; t < 675; t += 256) lpac[t] = 0.f;
    __syncthreads();
    int bid = blockIdx.x;
    int s = bid >> 6, sb = bid & 63;          // 512 blocks = 8 samples x 64
    int beg = s * 12500 + sb * 196;
    int end = min(s * 12500 + 12500, beg + 196);
    int c = tid & 31, nl = tid >> 5;
    for (int i = beg + nl; i < end; i += 8) {
        float z = y3[(size_t)i * 32 + c];     // RAW y3 (bn after pool)
        float px = pos[i * 3], py = pos[i * 3 + 1];
        int cx = min(max((int)floorf(px / 16.f), 0), 14);
        int cy = min(max((int)floorf(py / 12.f), 0), 14);
        int cl = cy * 15 + cx;
        atomicMax(&lkey[cl * 32 + c], enc_f(z));
        if (c == 0) {
            atomicAdd(&lcnt[cl], 1.f);
            atomicAdd(&lpac[cl * 3 + 0], px);
            atomicAdd(&lpac[cl * 3 + 1], py);
            atomicAdd(&lpac[cl * 3 + 2], pos[i * 3 + 2]);
        }
    }
    __syncthreads();
    for (int t = tid; t < 7200; t += 256) PK[(size_t)bid * 7200 + t] = lkey[t];
    if (tid < 225) PC[bid * 225 + tid] = lcnt[tid];
    for (int t = tid; t < 675; t += 256) PP[bid * 675 + t] = lpac[t];
}

// ---- pool3b + A4 fused: block owns 16 pooled nodes (R12-verified body) -----
__global__ __launch_bounds__(256)
void p3b_a4(const unsigned* __restrict__ PK, const float* __restrict__ PC,
            const float* __restrict__ PP, const float* __restrict__ ST3,
            const float* __restrict__ g3, const float* __restrict__ be3,
            float* __restrict__ X2, float* __restrict__ POS2,
            const float* __restrict__ wl, const float* __restrict__ wsrc,
            const float* __restrict__ wpos, const float* __restrict__ bpos,
            float4* __restrict__ SHPc, float2* __restrict__ CAPc) {
    __shared__ float x2l[16 * 33];
    __shared__ float pos2l[48];
    int tid = threadIdx.x, blk = blockIdx.x;
    int nb0 = blk * 16;
    // stage 1a: X2 = bn(merge-max over 64 partials) (empty -> 0)
    for (int t = tid; t < 512; t += 256) {
        int nl = t >> 5, c = t & 31;
        int n = nb0 + nl;
        if (n < NN_COARSE) {
            int s = n / 225, loc = n % 225;
            unsigned m = ENC_NEGINF;
#pragma unroll 8
            for (int sb = 0; sb < 64; ++sb)
                m = max(m, PK[(size_t)(s * 64 + sb) * 7200 + loc * 32 + c]);
            float2 ss = bn_ss(ST3, g3, be3, c, INV_N);
            float v = (m == ENC_NEGINF) ? 0.f : (dec_f(m) * ss.x + ss.y);
            x2l[nl * 33 + c] = v;
            X2[n * 32 + c] = v;
        }
    }
    // stage 1b: POS2 = sum(pacc)/cnt over 64 partials
    if (tid < 48) {
        int nl = tid / 3, r = tid % 3;
        int n = nb0 + nl;
        if (n < NN_COARSE) {
            int s = n / 225, loc = n % 225;
            float sp = 0.f, sc = 0.f;
#pragma unroll 8
            for (int sb = 0; sb < 64; ++sb) {
                sp += PP[(s * 64 + sb) * 675 + loc * 3 + r];
                sc += PC[(s * 64 + sb) * 225 + loc];
            }
            float v = sp / fmaxf(sc, 1.f);
            pos2l[tid] = v;
            POS2[n * 3 + r] = v;
        }
    }
    __syncthreads();
    // stage 2: A4 = pass<32,32,0> from LDS
    {
        int nl = tid >> 4, p = tid & 15;
        int n = nb0 + nl;
        if (n < NN_COARSE) {
            int c0 = 2 * p;
            float h0 = 0.f, a0 = 0.f, h1 = 0.f, a1 = 0.f;
#pragma unroll
            for (int r = 0; r < 32; ++r) {
                float fv = x2l[nl * 33 + r];
                float2 wlr = *reinterpret_cast<const float2*>(&wl[r * 32 + c0]);
                float2 wsr = *reinterpret_cast<const float2*>(&wsrc[r * 32 + c0]);
                h0 += fv * wlr.x; h1 += fv * wlr.y;
                a0 += fv * wsr.x; a1 += fv * wsr.y;
            }
            float px = pos2l[nl * 3], py = pos2l[nl * 3 + 1], pz = pos2l[nl * 3 + 2];
            float2 w0 = *reinterpret_cast<const float2*>(&wpos[c0]);
            float2 w1 = *reinterpret_cast<const float2*>(&wpos[32 + c0]);
            float2 w2 = *reinterpret_cast<const float2*>(&wpos[64 + c0]);
            float pd0 = px * w0.x + py * w1.x + pz * w2.x;
            float pd1 = px * w0.y + py * w1.y + pz * w2.y;
            float2 bp = *reinterpret_cast<const float2*>(&bpos[c0]);
            SHPc[(size_t)n * 16 + p] = make_float4(a0 + pd0, a1 + pd1, h0 - pd0, h1 - pd1);
            CAPc[(size_t)n * 16 + p] = make_float2(pd0 + bp.x, pd1 + bp.y);
        }
    }
}

// ---- A5 with fused S4: reduce E4's 113x64 partials in-block, then body -----
__global__ __launch_bounds__(256)
void a5_k(const float* __restrict__ PS, const float* __restrict__ g4,
          const float* __restrict__ be4, const float* __restrict__ Y4,
          const float* __restrict__ X2,
          const float* __restrict__ wl, const float* __restrict__ wsrc,
          const float* __restrict__ wpos, const float* __restrict__ bpos,
          const float* __restrict__ POS2,
          float4* __restrict__ SHPc, float2* __restrict__ CAPc) {
    __shared__ float red[64];
    __shared__ float2 ssl[32];
    int tid = threadIdx.x;
    if (tid < 64) {
        float s = 0.f;
#pragma unroll 4
        for (int r = 0; r < 113; ++r) s += PS[r * 64 + tid];
        red[tid] = s;
    }
    __syncthreads();
    if (tid < 32) {
        float mu = red[tid] * INV_N2;
        float var = fmaxf(red[32 + tid] * INV_N2 - mu * mu, 0.f);
        float sc = g4[tid] * rsqrtf(var + 1e-5f);
        ssl[tid] = make_float2(sc, be4[tid] - mu * sc);
    }
    __syncthreads();
    int u = blockIdx.x * 256 + tid;          // 450 blocks x 256 = 115200
    int i = u >> 6, p = u & 63;              // P = 64 (COUT=128)
    float f[32];
#pragma unroll
    for (int r = 0; r < 32; ++r) {
        float2 ss = ssl[r];
        f[r] = Y4[i * 32 + r] * ss.x + ss.y + X2[i * 32 + r];
    }
    int c0 = 2 * p;
    float h0 = 0.f, a0 = 0.f, h1 = 0.f, a1 = 0.f;
#pragma unroll
    for (int r = 0; r < 32; ++r) {
        float2 wlr = *reinterpret_cast<const float2*>(&wl[r * 128 + c0]);
        float2 wsr = *reinterpret_cast<const float2*>(&wsrc[r * 128 + c0]);
        h0 += f[r] * wlr.x; h1 += f[r] * wlr.y;
        a0 += f[r] * wsr.x; a1 += f[r] * wsr.y;
    }
    float px = POS2[i * 3], py = POS2[i * 3 + 1], pz = POS2[i * 3 + 2];
    float2 w0 = *reinterpret_cast<const float2*>(&wpos[c0]);
    float2 w1 = *reinterpret_cast<const float2*>(&wpos[128 + c0]);
    float2 w2 = *reinterpret_cast<const float2*>(&wpos[256 + c0]);
    float pd0 = px * w0.x + py * w1.x + pz * w2.x;
    float pd1 = px * w0.y + py * w1.y + pz * w2.y;
    float2 bp = *reinterpret_cast<const float2*>(&bpos[c0]);
    SHPc[(size_t)i * 64 + p] = make_float4(a0 + pd0, a1 + pd1, h0 - pd0, h1 - pd1);
    CAPc[(size_t)i * 64 + p] = make_float2(pd0 + bp.x, pd1 + bp.y);
}

// ---------------- pool5: one block per sample, LDS max, direct store --------
__global__ __launch_bounds__(1024)
void pool5_k(const float* __restrict__ y5, const float* __restrict__ st,
             const float* __restrict__ g, const float* __restrict__ be,
             const float* __restrict__ POS2, float* __restrict__ POOLED) {
    __shared__ unsigned lkey[2048];   // 16 cells x 128 ch
    int tid = threadIdx.x, s = blockIdx.x;
    for (int t = tid; t < 2048; t += 1024) lkey[t] = ENC_NEGINF;
    __syncthreads();
    int c = tid & 127, nl = tid >> 7;
    float2 ss = bn_ss(st, g, be, c, INV_N2);
    for (int j = nl; j < 225; j += 8) {
        int i = s * 225 + j;
        float z = y5[(size_t)i * 128 + c] * ss.x + ss.y;
        float px = POS2[i * 3], py = POS2[i * 3 + 1];
        int cx = min(max((int)floorf(px / 60.f), 0), 3);
        int cy = min(max((int)floorf(py / 45.f), 0), 3);
        atomicMax(&lkey[(cy * 4 + cx) * 128 + c], enc_f(z));
    }
    __syncthreads();
    for (int t = tid; t < 2048; t += 1024) {
        unsigned k = lkey[t];
        POOLED[s * 2048 + t] = (k == ENC_NEGINF) ? 0.f : dec_f(k);
    }
}

// ---------------- FC: 128 blocks = (8 samples x 16 k-chunks), coalesced -----
__global__ __launch_bounds__(256)
void fc_k(const float* __restrict__ POOLED, const float* __restrict__ wfc,
          float* __restrict__ out) {
    __shared__ float row[128];
    __shared__ float acc[256];
    int s = blockIdx.x, kc = blockIdx.y;
    int k0 = kc * 128;
    int tid = threadIdx.x;
    if (tid < 128) row[tid] = POOLED[s * 2048 + k0 + tid];
    __syncthreads();
    int o = tid & 127, half = tid >> 7;
    float a = 0.f;
    if (o < 101) {
        int kk0 = half * 64;
        for (int kk = kk0; kk < kk0 + 64; ++kk)
            a += row[kk] * wfc[(size_t)(k0 + kk) * 101 + o];
    }
    acc[tid] = a;
    __syncthreads();
    if (tid < 128 && o < 101)
        atomicAdd(&out[s * 101 + o], acc[tid] + acc[tid + 128]);
}

extern "C" void kernel_launch(void* const* d_in, const int* in_sizes, int n_in,
                              void* d_out, int out_size, void* d_ws, size_t ws_size,
                              hipStream_t stream) {
    const float* x     = (const float*)d_in[0];
    const float* pos   = (const float*)d_in[1];
    const int*   e1    = (const int*)d_in[3];
    const int*   e2    = (const int*)d_in[4];
    const float* w_fc  = (const float*)d_in[40];
    auto F = [&](int idx) { return (const float*)d_in[idx]; };

    float* W = (float*)d_ws;
    size_t o = 0;
    float4* SHPf = (float4*)W;        o += 6400000;  // N*16 floats (L1..L3)
    float2* CAPf = (float2*)(W + o);  o += 3200000;
    float*  Y1   = W + o;             o += 800000;
    float*  Y2   = W + o;             o += 800000;
    float*  Z1   = W + o;             o += 800000;
    float*  Y3   = W + o;             o += 3200000;
    float*  STATS = W + o;            o += 5 * 256;
    float*  X2   = W + o;             o += 57600;
    float*  POS2 = W + o;             o += 5400;
    float4* SHPc = (float4*)(W + o);  o += 460800;
    float2* CAPc = (float2*)(W + o);  o += 230400;
    float*  Y4   = W + o;             o += 57600;
    float*  Y5   = W + o;             o += 230400;
    float*  POOLED = W + o;           o += 16384;
    float*  PSTAT  = W + o;           o += 400000;   // max 6250 blocks * 64
    // pool3 partials alias the (dead after E3) SHPf region (6.4M floats):
    unsigned* PK = (unsigned*)W;                  // 512*7200 u32 = 3.69M
    float*    PC = W + 5600000;                   // 512*225 = 115200
    float*    PP = W + 5800000;                   // 512*675 = 345600

    // ---- L1 (1->8) fine (also zeroes STATS + out) ----
    hipLaunchKernelGGL((pass_a<1, 8, 0>), dim3(1563), dim3(256), 0, stream,
                       x, nullptr, nullptr, nullptr, 0.f, nullptr,
                       F(5), F(6), F(8), F(9), pos, SHPf, CAPf, nullptr, 400000,
                       STATS, (float*)d_out);
    hipLaunchKernelGGL((edge_pass<8, false>), dim3(1563), dim3(256), 0, stream,
                       SHPf, CAPf, e1, (float2*)Y1, PSTAT, NN_FINE);
    hipLaunchKernelGGL((stats_r<8>), dim3(32), dim3(256), 0, stream,
                       PSTAT, 1563, STATS + 0);

    // ---- L2 (8->8) fine, writes Z1=bn(Y1) ----
    hipLaunchKernelGGL((pass_a<8, 8, 1>), dim3(1563), dim3(256), 0, stream,
                       Y1, STATS + 0, F(10), F(11), INV_N, nullptr,
                       F(12), F(13), F(15), F(16), pos, SHPf, CAPf, Z1, 400000,
                       nullptr, nullptr);
    hipLaunchKernelGGL((edge_pass<8, false>), dim3(1563), dim3(256), 0, stream,
                       SHPf, CAPf, e1, (float2*)Y2, PSTAT, NN_FINE);
    hipLaunchKernelGGL((stats_r<8>), dim3(32), dim3(256), 0, stream,
                       PSTAT, 1563, STATS + 256);

    // ---- L3 (8->32) fine, f = bn(Y2)+Z1 ----
    hipLaunchKernelGGL((pass_a<8, 32, 2>), dim3(6250), dim3(256), 0, stream,
                       Y2, STATS + 256, F(17), F(18), INV_N, Z1,
                       F(19), F(20), F(22), F(23), pos, SHPf, CAPf, nullptr, 1600000,
                       nullptr, nullptr);
    hipLaunchKernelGGL((edge_pass<32, false>), dim3(6250), dim3(256), 0, stream,
                       SHPf, CAPf, e1, (float2*)Y3, PSTAT, NN_FINE);
    hipLaunchKernelGGL((stats_r<32>), dim3(32), dim3(256), 0, stream,
                       PSTAT, 6250, STATS + 512);

    // ---- pool3: 512-block raw-max partials ----
    hipLaunchKernelGGL(pool3a, dim3(512), dim3(256), 0, stream,
                       Y3, pos, PK, PC, PP);

    // ---- pool3b + A4 fused ----
    hipLaunchKernelGGL(p3b_a4, dim3(113), dim3(256), 0, stream,
                       PK, PC, PP, STATS + 512, F(24), F(25), X2, POS2,
                       F(26), F(27), F(29), F(30), SHPc, CAPc);

    // ---- E4 (coarse) -> partial rows ----
    hipLaunchKernelGGL((edge_pass<32, true>), dim3(113), dim3(256), 0, stream,
                       SHPc, CAPc, e2, (float2*)Y4, PSTAT, NN_COARSE);

    // ---- A5 with fused S4 ----
    hipLaunchKernelGGL(a5_k, dim3(450), dim3(256), 0, stream,
                       PSTAT, F(31), F(32), Y4, X2,
                       F(33), F(34), F(36), F(37), POS2, SHPc, CAPc);

    // ---- E5 + S5 ----
    hipLaunchKernelGGL((edge_pass<128, true>), dim3(450), dim3(256), 0, stream,
                       SHPc, CAPc, e2, (float2*)Y5, PSTAT, NN_COARSE);
    hipLaunchKernelGGL((stats_r<128>), dim3(16), dim3(256), 0, stream,
                       PSTAT, 450, STATS + 1024);

    // ---- pool5 + FC ----
    hipLaunchKernelGGL(pool5_k, dim3(8), dim3(1024), 0, stream,
                       Y5, STATS + 1024, F(38), F(39), POS2, POOLED);
    hipLaunchKernelGGL(fc_k, dim3(8, 16), dim3(256), 0, stream,
                       POOLED, w_fc, (float*)d_out);
}

// Round 15
// 213.920 us; speedup vs baseline: 1.0663x; 1.0663x over previous
//
#include <hip/hip_runtime.h>

#define ENC_NEGINF 0x007FFFFFu
#define NN_FINE 100000
#define NN_COARSE 1800
#define INV_N  (1.0f / 100000.0f)
#define INV_N2 (1.0f / 1800.0f)

__device__ __forceinline__ unsigned enc_f(float f) {
    unsigned u = __float_as_uint(f);
    return (u & 0x80000000u) ? ~u : (u | 0x80000000u);
}
__device__ __forceinline__ float dec_f(unsigned k) {
    return (k & 0x80000000u) ? __uint_as_float(k & 0x7fffffffu) : __uint_as_float(~k);
}

// bijective XCD-aware swizzle (m204 variant)
__device__ __forceinline__ int xcd_swz(int bid, int nwg) {
    int q = nwg >> 3, r = nwg & 7;
    int xcd = bid & 7, idx = bid >> 3;
    return (xcd < r ? xcd * (q + 1) : r * (q + 1) + (xcd - r) * q) + idx;
}

__device__ __forceinline__ float2 bn_ss(const float* __restrict__ st,
                                        const float* __restrict__ g,
                                        const float* __restrict__ be,
                                        int r, float invn) {
    float mu  = st[r] * invn;
    float var = fmaxf(st[128 + r] * invn - mu * mu, 0.f);
    float s = g[r] * rsqrtf(var + 1e-5f);
    return make_float2(s, be[r] - mu * s);
}

// ---------------- PassA; A1 also zeroes STATS + out --------------------------
// MODE 0: f=in. 1: f=bn(in), write zout=bn(in). 2: f=bn(in)+skipf.
template<int CIN, int COUT, int MODE>
__global__ void pass_a(const float* __restrict__ in,
                       const float* __restrict__ st, const float* __restrict__ g,
                       const float* __restrict__ be, float invn,
                       const float* __restrict__ skipf,
                       const float* __restrict__ wl, const float* __restrict__ wsrc,
                       const float* __restrict__ wpos, const float* __restrict__ bpos,
                       const float* __restrict__ pos,
                       float4* __restrict__ SHP, float2* __restrict__ CAP,
                       float* __restrict__ zout, int total,
                       float* __restrict__ zstats, float* __restrict__ zo) {
    constexpr int P = COUT / 2;
    int idx = blockIdx.x * blockDim.x + threadIdx.x;
    if (zstats) {                    // A1 only: init atomic targets
        if (idx < 1280) zstats[idx] = 0.f;
        if (idx < 808)  zo[idx] = 0.f;
    }
    if (idx >= total) return;
    int i = idx / P, p = idx % P;
    float f[CIN];
#pragma unroll
    for (int r = 0; r < CIN; ++r) {
        float v = in[i * CIN + r];
        if constexpr (MODE >= 1) {
            float2 ss = bn_ss(st, g, be, r, invn);
            v = v * ss.x + ss.y;
        }
        if constexpr (MODE == 2) v += skipf[i * CIN + r];
        f[r] = v;
    }
    int c0 = 2 * p;
    float h0 = 0.f, a0 = 0.f, h1 = 0.f, a1 = 0.f;
#pragma unroll
    for (int r = 0; r < CIN; ++r) {
        float2 wlr = *reinterpret_cast<const float2*>(&wl[r * COUT + c0]);
        float2 wsr = *reinterpret_cast<const float2*>(&wsrc[r * COUT + c0]);
        h0 += f[r] * wlr.x; h1 += f[r] * wlr.y;
        a0 += f[r] * wsr.x; a1 += f[r] * wsr.y;
    }
    float px = pos[i * 3], py = pos[i * 3 + 1], pz = pos[i * 3 + 2];
    float2 w0 = *reinterpret_cast<const float2*>(&wpos[c0]);
    float2 w1 = *reinterpret_cast<const float2*>(&wpos[COUT + c0]);
    float2 w2 = *reinterpret_cast<const float2*>(&wpos[2 * COUT + c0]);
    float pd0 = px * w0.x + py * w1.x + pz * w2.x;
    float pd1 = px * w0.y + py * w1.y + pz * w2.y;
    float2 bp = *reinterpret_cast<const float2*>(&bpos[c0]);
    SHP[(size_t)i * P + p] = make_float4(a0 + pd0, a1 + pd1, h0 - pd0, h1 - pd1);
    CAP[(size_t)i * P + p] = make_float2(pd0 + bp.x, pd1 + bp.y);
    if constexpr (MODE == 1) {
        float2 s0 = bn_ss(st, g, be, c0, invn);
        float2 s1 = bn_ss(st, g, be, c0 + 1, invn);
        float2 zv = make_float2(in[i * CIN + c0] * s0.x + s0.y,
                                in[i * CIN + c0 + 1] * s1.x + s1.y);
        *reinterpret_cast<float2*>(&zout[i * CIN + c0]) = zv;
    }
}

// ---- Edge pass: 1 float4 gather per edge + BN-stats partial rows -----------
template<int C, bool COARSE>
__global__ __launch_bounds__(256, 4)
void edge_pass(const float4* __restrict__ SHP, const float2* __restrict__ CAP,
               const int* __restrict__ esrc, float2* __restrict__ y2,
               float* __restrict__ PS, int NN) {
    constexpr int P = C / 2;
    constexpr int NPB = 256 / P;
    constexpr int DEG_ = COARSE ? 8 : 16;
    __shared__ int se[NPB * DEG_];
    __shared__ float ls[C], lq[C];
    int bid = COARSE ? (int)blockIdx.x : xcd_swz(blockIdx.x, gridDim.x);
    int tid = threadIdx.x;
    int node0 = bid * NPB;
    if constexpr (!COARSE) {
        for (int t = tid; t < NPB * DEG_; t += 256)
            se[t] = esrc[node0 * 16 + t];          // in-bounds: dst half follows src
    } else {
        for (int t = tid; t < NPB * DEG_; t += 256) {
            int n = t / DEG_, e = t % DEG_;
            int i2 = node0 + n;
            if (i2 < NN) {
                int b = i2 / 225, j = i2 % 225;
                se[t] = esrc[b * 1800 + e * 225 + j];
            }
        }
    }
    if (tid < C) { ls[tid] = 0.f; lq[tid] = 0.f; }
    __syncthreads();
    int n = tid / P, p = tid % P;
    int i = node0 + n;
    float y0 = 0.f, y1 = 0.f;
    if (i < NN) {
        float4 q[DEG_ + 1];
#pragma unroll
        for (int e = 0; e < DEG_; ++e)
            q[e] = SHP[(size_t)se[n * DEG_ + e] * P + p];
        q[DEG_] = SHP[(size_t)i * P + p];

        float smin0 = q[0].x, smin1 = q[0].y;
#pragma unroll
        for (int e = 1; e <= DEG_; ++e) {
            smin0 = fminf(smin0, q[e].x);
            smin1 = fminf(smin1, q[e].y);
        }
        float den0 = 0.f, acc0 = 0.f, den1 = 0.f, acc1 = 0.f;
#pragma unroll
        for (int e = 0; e <= DEG_; ++e) {
            float ex0 = __expf(smin0 - q[e].x);
            float ex1 = __expf(smin1 - q[e].y);
            den0 += ex0; acc0 += ex0 * q[e].z;
            den1 += ex1; acc1 += ex1 * q[e].w;
        }
        float2 Ci = CAP[(size_t)i * P + p];
        float o0 = (acc0 + Ci.x * den0) / (den0 + 1e-16f);
        float o1 = (acc1 + Ci.y * den1) / (den1 + 1e-16f);
        y0 = o0 > 0.f ? o0 : (__expf(o0) - 1.f);
        y1 = o1 > 0.f ? o1 : (__expf(o1) - 1.f);
        y2[(size_t)i * P + p] = make_float2(y0, y1);
    }
    float sa0 = y0, sq0 = y0 * y0, sa1 = y1, sq1 = y1 * y1;
    if constexpr (P < 64) {
#pragma unroll
        for (int m = P; m < 64; m <<= 1) {
            sa0 += __shfl_xor(sa0, m); sa1 += __shfl_xor(sa1, m);
            sq0 += __shfl_xor(sq0, m); sq1 += __shfl_xor(sq1, m);
        }
    }
    if ((tid & 63) < P) {
        int c0 = 2 * p;
        atomicAdd(&ls[c0], sa0); atomicAdd(&ls[c0 + 1], sa1);
        atomicAdd(&lq[c0], sq0); atomicAdd(&lq[c0 + 1], sq1);
    }
    __syncthreads();
    if (tid < C) {
        PS[(size_t)blockIdx.x * 2 * C + tid]     = ls[tid];
        PS[(size_t)blockIdx.x * 2 * C + C + tid] = lq[tid];
    }
}

// ------- stats reduce: nb per-block partials -> STATS (multi-block) ---------
template<int C>
__global__ __launch_bounds__(256)
void stats_r(const float* __restrict__ PS, int nb, float* __restrict__ STATS) {
    constexpr int TC = 2 * C;
    constexpr int NS = 256 / TC;
    __shared__ float acc[256];
    int tid = threadIdx.x;
    int c = tid % TC, sl = tid / TC;
    float s = 0.f;
    for (int b = blockIdx.x * NS + sl; b < nb; b += gridDim.x * NS)
        s += PS[(size_t)b * TC + c];
    acc[tid] = s;
    __syncthreads();
    if (tid < TC) {
        float t = 0.f;
#pragma unroll
        for (int s2 = 0; s2 < NS; ++s2) t += acc[s2 * TC + tid];
        float* dst = (tid < C) ? &STATS[tid] : &STATS[128 + (tid - C)];
        atomicAdd(dst, t);
    }
}

// ---- pool3a: 64 blocks/sample, RAW-max private-LDS partials -----------------
__global__ __launch_bounds__(256)
void pool3a(const float* __restrict__ y3, const float* __restrict__ pos,
            unsigned* __restrict__ PK, float* __restrict__ PC,
            float* __restrict__ PP) {
    __shared__ unsigned lkey[7200];
    __shared__ float lcnt[225];
    __shared__ float lpac[675];
    int tid = threadIdx.x;
    for (int t = tid; t < 7200; t += 256) lkey[t] = ENC_NEGINF;
    if (tid < 225) lcnt[tid] = 0.f;
    for (int t = tid; t < 675; t += 256) lpac[t] = 0.f;
    __syncthreads();
    int bid = blockIdx.x;
    int s = bid >> 6, sb = bid & 63;          // 512 blocks = 8 samples x 64
    int beg = s * 12500 + sb * 196;
    int end = min(s * 12500 + 12500, beg + 196);
    int c = tid & 31, nl = tid >> 5;
    for (int i = beg + nl; i < end; i += 8) {
        float z = y3[(size_t)i * 32 + c];     // RAW y3 (bn after pool)
        float px = pos[i * 3], py = pos[i * 3 + 1];
        int cx = min(max((int)floorf(px / 16.f), 0), 14);
        int cy = min(max((int)floorf(py / 12.f), 0), 14);
        int cl = cy * 15 + cx;
        atomicMax(&lkey[cl * 32 + c], enc_f(z));
        if (c == 0) {
            atomicAdd(&lcnt[cl], 1.f);
            atomicAdd(&lpac[cl * 3 + 0], px);
            atomicAdd(&lpac[cl * 3 + 1], py);
            atomicAdd(&lpac[cl * 3 + 2], pos[i * 3 + 2]);
        }
    }
    __syncthreads();
    for (int t = tid; t < 7200; t += 256) PK[(size_t)bid * 7200 + t] = lkey[t];
    if (tid < 225) PC[bid * 225 + tid] = lcnt[tid];
    for (int t = tid; t < 675; t += 256) PP[bid * 675 + t] = lpac[t];
}

// ---- pool3b: merge 64 partials -> X2 = bn(max) (empty->0), POS2 ------------
__global__ void pool3b(const unsigned* __restrict__ PK, const float* __restrict__ PC,
                       const float* __restrict__ PP, const float* __restrict__ ST3,
                       const float* __restrict__ g3, const float* __restrict__ be3,
                       float* __restrict__ X2, float* __restrict__ POS2) {
    int idx = blockIdx.x * blockDim.x + threadIdx.x;
    if (idx < 57600) {
        int s = idx / 7200, t = idx % 7200;
        unsigned m = ENC_NEGINF;
#pragma unroll 8
        for (int sb = 0; sb < 64; ++sb)
            m = max(m, PK[(size_t)(s * 64 + sb) * 7200 + t]);
        float2 ss = bn_ss(ST3, g3, be3, t & 31, INV_N);
        X2[idx] = (m == ENC_NEGINF) ? 0.f : (dec_f(m) * ss.x + ss.y);
    } else if (idx < 63000) {
        int j = idx - 57600;
        int s = j / 675, r = j % 675;
        int cl = r / 3;
        float sp = 0.f, sc = 0.f;
#pragma unroll 8
        for (int sb = 0; sb < 64; ++sb) {
            sp += PP[(s * 64 + sb) * 675 + r];
            sc += PC[(s * 64 + sb) * 225 + cl];
        }
        POS2[j] = sp / fmaxf(sc, 1.f);
    }
}

// ---------------- pool5: one block per sample, LDS max, direct store --------
__global__ __launch_bounds__(1024)
void pool5_k(const float* __restrict__ y5, const float* __restrict__ st,
             const float* __restrict__ g, const float* __restrict__ be,
             const float* __restrict__ POS2, float* __restrict__ POOLED) {
    __shared__ unsigned lkey[2048];   // 16 cells x 128 ch
    int tid = threadIdx.x, s = blockIdx.x;
    for (int t = tid; t < 2048; t += 1024) lkey[t] = ENC_NEGINF;
    __syncthreads();
    int c = tid & 127, nl = tid >> 7;
    float2 ss = bn_ss(st, g, be, c, INV_N2);
    for (int j = nl; j < 225; j += 8) {
        int i = s * 225 + j;
        float z = y5[(size_t)i * 128 + c] * ss.x + ss.y;
        float px = POS2[i * 3], py = POS2[i * 3 + 1];
        int cx = min(max((int)floorf(px / 60.f), 0), 3);
        int cy = min(max((int)floorf(py / 45.f), 0), 3);
        atomicMax(&lkey[(cy * 4 + cx) * 128 + c], enc_f(z));
    }
    __syncthreads();
    for (int t = tid; t < 2048; t += 1024) {
        unsigned k = lkey[t];
        POOLED[s * 2048 + t] = (k == ENC_NEGINF) ? 0.f : dec_f(k);
    }
}

// ---------------- FC: 128 blocks = (8 samples x 16 k-chunks), coalesced -----
__global__ __launch_bounds__(256)
void fc_k(const float* __restrict__ POOLED, const float* __restrict__ wfc,
          float* __restrict__ out) {
    __shared__ float row[128];
    __shared__ float acc[256];
    int s = blockIdx.x, kc = blockIdx.y;
    int k0 = kc * 128;
    int tid = threadIdx.x;
    if (tid < 128) row[tid] = POOLED[s * 2048 + k0 + tid];
    __syncthreads();
    int o = tid & 127, half = tid >> 7;
    float a = 0.f;
    if (o < 101) {
        int kk0 = half * 64;
        for (int kk = kk0; kk < kk0 + 64; ++kk)
            a += row[kk] * wfc[(size_t)(k0 + kk) * 101 + o];
    }
    acc[tid] = a;
    __syncthreads();
    if (tid < 128 && o < 101)
        atomicAdd(&out[s * 101 + o], acc[tid] + acc[tid + 128]);
}

extern "C" void kernel_launch(void* const* d_in, const int* in_sizes, int n_in,
                              void* d_out, int out_size, void* d_ws, size_t ws_size,
                              hipStream_t stream) {
    const float* x     = (const float*)d_in[0];
    const float* pos   = (const float*)d_in[1];
    const int*   e1    = (const int*)d_in[3];
    const int*   e2    = (const int*)d_in[4];
    const float* w_fc  = (const float*)d_in[40];
    auto F = [&](int idx) { return (const float*)d_in[idx]; };

    float* W = (float*)d_ws;
    size_t o = 0;
    float4* SHPf = (float4*)W;        o += 6400000;  // N*16 floats (L1..L3)
    float2* CAPf = (float2*)(W + o);  o += 3200000;
    float*  Y1   = W + o;             o += 800000;
    float*  Y2   = W + o;             o += 800000;
    float*  Z1   = W + o;             o += 800000;
    float*  Y3   = W + o;             o += 3200000;
    float*  STATS = W + o;            o += 5 * 256;
    float*  X2   = W + o;             o += 57600;
    float*  POS2 = W + o;             o += 5400;
    float4* SHPc = (float4*)(W + o);  o += 460800;
    float2* CAPc = (float2*)(W + o);  o += 230400;
    float*  Y4   = W + o;             o += 57600;
    float*  Y5   = W + o;             o += 230400;
    float*  POOLED = W + o;           o += 16384;
    float*  PSTAT  = W + o;           o += 400000;   // max 6250 blocks * 64
    // pool3 partials alias the (dead after E3) SHPf region (6.4M floats):
    unsigned* PK = (unsigned*)W;                  // 512*7200 u32 = 3.69M
    float*    PC = W + 5600000;                   // 512*225 = 115200
    float*    PP = W + 5800000;                   // 512*675 = 345600

    // ---- L1 (1->8) fine (also zeroes STATS + out) ----
    hipLaunchKernelGGL((pass_a<1, 8, 0>), dim3(1563), dim3(256), 0, stream,
                       x, nullptr, nullptr, nullptr, 0.f, nullptr,
                       F(5), F(6), F(8), F(9), pos, SHPf, CAPf, nullptr, 400000,
                       STATS, (float*)d_out);
    hipLaunchKernelGGL((edge_pass<8, false>), dim3(1563), dim3(256), 0, stream,
                       SHPf, CAPf, e1, (float2*)Y1, PSTAT, NN_FINE);
    hipLaunchKernelGGL((stats_r<8>), dim3(32), dim3(256), 0, stream,
                       PSTAT, 1563, STATS + 0);

    // ---- L2 (8->8) fine, writes Z1=bn(Y1) ----
    hipLaunchKernelGGL((pass_a<8, 8, 1>), dim3(1563), dim3(256), 0, stream,
                       Y1, STATS + 0, F(10), F(11), INV_N, nullptr,
                       F(12), F(13), F(15), F(16), pos, SHPf, CAPf, Z1, 400000,
                       nullptr, nullptr);
    hipLaunchKernelGGL((edge_pass<8, false>), dim3(1563), dim3(256), 0, stream,
                       SHPf, CAPf, e1, (float2*)Y2, PSTAT, NN_FINE);
    hipLaunchKernelGGL((stats_r<8>), dim3(32), dim3(256), 0, stream,
                       PSTAT, 1563, STATS + 256);

    // ---- L3 (8->32) fine, f = bn(Y2)+Z1 ----
    hipLaunchKernelGGL((pass_a<8, 32, 2>), dim3(6250), dim3(256), 0, stream,
                       Y2, STATS + 256, F(17), F(18), INV_N, Z1,
                       F(19), F(20), F(22), F(23), pos, SHPf, CAPf, nullptr, 1600000,
                       nullptr, nullptr);
    hipLaunchKernelGGL((edge_pass<32, false>), dim3(6250), dim3(256), 0, stream,
                       SHPf, CAPf, e1, (float2*)Y3, PSTAT, NN_FINE);
    hipLaunchKernelGGL((stats_r<32>), dim3(32), dim3(256), 0, stream,
                       PSTAT, 6250, STATS + 512);

    // ---- pool3: 512-block raw-max partials, then 64-way merge + bn ----
    hipLaunchKernelGGL(pool3a, dim3(512), dim3(256), 0, stream,
                       Y3, pos, PK, PC, PP);
    hipLaunchKernelGGL(pool3b, dim3(247), dim3(256), 0, stream,
                       PK, PC, PP, STATS + 512, F(24), F(25), X2, POS2);

    // ---- L4 (32->32) coarse ----
    hipLaunchKernelGGL((pass_a<32, 32, 0>), dim3(113), dim3(256), 0, stream,
                       X2, nullptr, nullptr, nullptr, 0.f, nullptr,
                       F(26), F(27), F(29), F(30), POS2, SHPc, CAPc, nullptr, 28800,
                       nullptr, nullptr);
    hipLaunchKernelGGL((edge_pass<32, true>), dim3(113), dim3(256), 0, stream,
                       SHPc, CAPc, e2, (float2*)Y4, PSTAT, NN_COARSE);
    hipLaunchKernelGGL((stats_r<32>), dim3(16), dim3(256), 0, stream,
                       PSTAT, 113, STATS + 768);

    // ---- L5 (32->128) coarse, f = bn(Y4)+X2 ----
    hipLaunchKernelGGL((pass_a<32, 128, 2>), dim3(450), dim3(256), 0, stream,
                       Y4, STATS + 768, F(31), F(32), INV_N2, X2,
                       F(33), F(34), F(36), F(37), POS2, SHPc, CAPc, nullptr, 115200,
                       nullptr, nullptr);
    hipLaunchKernelGGL((edge_pass<128, true>), dim3(450), dim3(256), 0, stream,
                       SHPc, CAPc, e2, (float2*)Y5, PSTAT, NN_COARSE);
    hipLaunchKernelGGL((stats_r<128>), dim3(16), dim3(256), 0, stream,
                       PSTAT, 450, STATS + 1024);

    // ---- pool5 + FC ----
    hipLaunchKernelGGL(pool5_k, dim3(8), dim3(1024), 0, stream,
                       Y5, STATS + 1024, F(38), F(39), POS2, POOLED);
    hipLaunchKernelGGL(fc_k, dim3(8, 16), dim3(256), 0, stream,
                       POOLED, w_fc, (float*)d_out);
}